// Round 1
// baseline (246.349 us; speedup 1.0000x reference)
//
#include <hip/hip_runtime.h>

// out[n,c,h,w] = sum_{c'} g[(c-c') mod 128] * act[n,c',h,w]
// where g = ifft(1 / fft(delta - k)), k = rolled zero-padded Ricker filter.
// C=128, S=H*W=4096 per image, 64 images.

typedef short bf16x8 __attribute__((ext_vector_type(8)));
typedef float f32x4 __attribute__((ext_vector_type(4)));

#define MFMA16x16x32 __builtin_amdgcn_mfma_f32_16x16x32_bf16

__device__ __forceinline__ unsigned short f2bf(float f) {
  union { float f; unsigned u; } v; v.f = f;
  unsigned u = v.u;
  u += 0x7fffu + ((u >> 16) & 1u);   // round-to-nearest-even
  return (unsigned short)(u >> 16);
}

// ---------------------------------------------------------------------------
// Setup: compute g[128] (fp32) from the 27-tap filter. One block, 128 threads.
// kf[j] = filt[t] at j=(115+t)&127 (pad_left=50, roll by 65).
// Fk[m] = 1 - sum_t kf*e^{-2pi i j m/128};  g[n] = (1/128) Re sum_m e^{+2pi i mn/128}/Fk[m]
// ---------------------------------------------------------------------------
__global__ void build_g(const float* __restrict__ filt, float* __restrict__ g) {
  __shared__ float ct[128], st[128], fr[128], fi[128];
  const int t = threadIdx.x;  // 0..127
  const float ang = (float)t * 0.049087385212340526f;  // 2*pi/128
  float s, c;
  __sincosf(ang, &s, &c);
  ct[t] = c; st[t] = s;
  __syncthreads();

  // forward DFT of (delta - kf) at frequency m=t
  float re = 1.f, im = 0.f;
  for (int tt = 0; tt < 27; ++tt) {
    const int j = (115 + tt) & 127;
    const int idx = (j * t) & 127;
    const float kv = filt[tt];
    re -= kv * ct[idx];   // e^{-i a} = cos a - i sin a
    im += kv * st[idx];
  }
  fr[t] = re; fi[t] = im;
  __syncthreads();

  // inverse DFT of 1/Fk at position n=t (real part)
  float acc = 0.f;
  for (int m = 0; m < 128; ++m) {
    const int idx = (m * t) & 127;
    const float dr = fr[m], di = fi[m];
    acc += (ct[idx] * dr + st[idx] * di) / (dr * dr + di * di);
  }
  g[t] = acc * (1.0f / 128.0f);
}

// ---------------------------------------------------------------------------
// Main kernel: per block (256 thr = 4 waves): one image n, one 128-wide s-tile.
// Wave w computes output rows c in [32w, 32w+32), all 128 s columns, K=128.
// LDS: X-tile transposed to [s][c'] bf16, pitch 136 (16B-aligned rows).
// ---------------------------------------------------------------------------
__global__ __launch_bounds__(256) void conv_inhib(
    const float* __restrict__ X, const float* __restrict__ gtab,
    float* __restrict__ Y) {
  __shared__ __align__(16) unsigned short Xt[128 * 136];  // [s][c'] bf16, ~34 KB
  __shared__ float gs[128];

  const int tid = threadIdx.x;
  const int l = tid & 63;        // lane in wave
  const int w = tid >> 6;        // wave id 0..3
  const int lane15 = l & 15;
  const int quad = l >> 4;

  const int bid = blockIdx.x;          // 0..2047
  const int nimg = bid >> 5;           // 0..63
  const int s0 = (bid & 31) << 7;      // s-tile origin (128 cols)
  const float* Xn = X + (size_t)nimg * (128 * 4096);
  float* Yn = Y + (size_t)nimg * (128 * 4096);

  if (tid < 128) gs[tid] = gtab[tid];

  // ---- Stage X tile: global (coalesced, float4) -> LDS transposed bf16 ----
  {
    const int ssub = (tid & 31) << 2;  // 4 consecutive s per thread
    const int cbase = tid >> 5;        // 0..7
#pragma unroll
    for (int r = 0; r < 16; ++r) {
      const int c = cbase + (r << 3);  // 0..127
      const float4 v = *(const float4*)(Xn + (size_t)c * 4096 + s0 + ssub);
      unsigned short* dst = &Xt[c];
      dst[(ssub + 0) * 136] = f2bf(v.x);
      dst[(ssub + 1) * 136] = f2bf(v.y);
      dst[(ssub + 2) * 136] = f2bf(v.z);
      dst[(ssub + 3) * 136] = f2bf(v.w);
    }
  }
  __syncthreads();

  // ---- Build persistent A fragments: A[m][k] = g[(m-k)&127] ----
  // layout: lane holds A[m=lane&15][k=quad*8+j]  (16x16x32 bf16)
  bf16x8 afrag[2][4];
#pragma unroll
  for (int i = 0; i < 2; ++i) {
    const int m = (w << 5) + (i << 4) + lane15;
#pragma unroll
    for (int kk = 0; kk < 4; ++kk) {
      const int kbase = (kk << 5) + (quad << 3);
#pragma unroll
      for (int j = 0; j < 8; ++j) {
        afrag[i][kk][j] = (short)f2bf(gs[(m - (kbase + j)) & 127]);
      }
    }
  }

  // ---- GEMM: D[m][n] = sum_k A[m][k] * Xt[n][k] ----
  f32x4 acc[2][8];
#pragma unroll
  for (int i = 0; i < 2; ++i)
#pragma unroll
    for (int ns = 0; ns < 8; ++ns)
      acc[i][ns] = (f32x4){0.f, 0.f, 0.f, 0.f};

#pragma unroll
  for (int ns = 0; ns < 8; ++ns) {
    const int srow = (ns << 4) + lane15;  // n = ns*16 + (lane&15)
#pragma unroll
    for (int kk = 0; kk < 4; ++kk) {
      // B[k=quad*8+j][n=lane&15] = Xt[srow][kk*32 + quad*8 + j]
      const bf16x8 b = *(const bf16x8*)&Xt[srow * 136 + (kk << 5) + (quad << 3)];
      acc[0][ns] = MFMA16x16x32(afrag[0][kk], b, acc[0][ns], 0, 0, 0);
      acc[1][ns] = MFMA16x16x32(afrag[1][kk], b, acc[1][ns], 0, 0, 0);
    }
  }

  // ---- Epilogue: C/D layout col=lane&15 (n), row=quad*4+reg (m) ----
#pragma unroll
  for (int i = 0; i < 2; ++i) {
#pragma unroll
    for (int r = 0; r < 4; ++r) {
      const int c = (w << 5) + (i << 4) + (quad << 2) + r;
      float* Yc = Yn + (size_t)c * 4096 + s0 + lane15;
#pragma unroll
      for (int ns = 0; ns < 8; ++ns) {
        Yc[ns << 4] = acc[i][ns][r];
      }
    }
  }
}

extern "C" void kernel_launch(void* const* d_in, const int* in_sizes, int n_in,
                              void* d_out, int out_size, void* d_ws, size_t ws_size,
                              hipStream_t stream) {
  const float* act = (const float*)d_in[0];   // (64,128,64,64) fp32
  const float* filt = (const float*)d_in[1];  // 27 fp32
  float* out = (float*)d_out;                 // (64,128,64,64) fp32
  float* g = (float*)d_ws;                    // 128 fp32 scratch

  build_g<<<1, 128, 0, stream>>>(filt, g);
  conv_inhib<<<2048, 256, 0, stream>>>(act, g, out);
}